// Round 6
// baseline (395.748 us; speedup 1.0000x reference)
//
#include <hip/hip_runtime.h>
#include <math.h>

#define N_NODES 100000
#define N_EDGES 1600000
#define C_DIM 40

#define BSZ 256                           // nodes per bucket
#define NB  ((N_NODES + BSZ - 1) / BSZ)   // 391
#define EB  4096                          // edges per hist/scatter block
#define NBE ((N_EDGES + EB - 1) / EB)     // 391

// ---------------- workspace layout (4-byte units) ----------------
#define OFF_DINV 0                        // float[100000]
#define OFF_BB   100000                   // int[NB+1]
#define OFF_ROW  100400                   // int[N+1]
#define OFF_H    200402                   // int[NBE*NB]
#define OFF_REC2 353284                   // int2[E] sorted records (even -> 8B aligned)
#define OFF_H1P  3553284                  // ushort[N*64] bf16 h1'; unsorted rec aliases here
#define OFF_H2P  6753284                  // ushort[N*40] bf16 h2'
// total ~8.75M ints = 35 MB

__device__ inline float rlane(float v, int k) {
    return __int_as_float(__builtin_amdgcn_readlane(__float_as_int(v), k));
}
__device__ inline unsigned short f2bf(float f) {
    unsigned int u = __float_as_uint(f);
    u += 0x7FFF + ((u >> 16) & 1);        // round to nearest even
    return (unsigned short)(u >> 16);
}
__device__ inline float bf2f(unsigned short h) {
    return __uint_as_float(((unsigned int)h) << 16);
}

// ---------- per-block bucket histogram: H[b][j] ----------
__global__ __launch_bounds__(512) void k_hist2d(const int* __restrict__ ei, int* __restrict__ H) {
    __shared__ int bins[NB];
    int t = threadIdx.x, b = blockIdx.x;
    for (int i = t; i < NB; i += 512) bins[i] = 0;
    __syncthreads();
    int base = b * EB;
    for (int i = t; i < EB; i += 512) {
        int e = base + i;
        if (e < N_EDGES) atomicAdd(&bins[ei[N_EDGES + e] >> 8], 1);
    }
    __syncthreads();
    for (int i = t; i < NB; i += 512) H[b * NB + i] = bins[i];
}

// ---------- bucketBase = exclusive scan of column sums (1 block) ----------
__global__ __launch_bounds__(512) void k_bucketsum(const int* __restrict__ H,
                                                   int* __restrict__ bucketBase,
                                                   int* __restrict__ rowStart) {
    __shared__ int sd[512];
    int t = threadIdx.x;
    int val = 0;
    if (t < NB)
        for (int b = 0; b < NBE; ++b) val += H[b * NB + t];
    sd[t] = val;
    __syncthreads();
    for (int off = 1; off < 512; off <<= 1) {
        int v = (t >= off) ? sd[t - off] : 0;
        __syncthreads();
        sd[t] += v;
        __syncthreads();
    }
    if (t < NB) bucketBase[t] = sd[t] - val;
    if (t == NB - 1) bucketBase[NB] = sd[t];
    if (t == 0) rowStart[N_NODES] = N_EDGES;
}

// ---------- column scan: H[b][j] -> bucketBase[j] + prefix_b (in place) ----------
__global__ __launch_bounds__(512) void k_colscan(int* __restrict__ H,
                                                 const int* __restrict__ bucketBase) {
    __shared__ int sd[512];
    int t = threadIdx.x, j = blockIdx.x;
    int val = (t < NBE) ? H[t * NB + j] : 0;
    sd[t] = val;
    __syncthreads();
    for (int off = 1; off < 512; off <<= 1) {
        int v = (t >= off) ? sd[t - off] : 0;
        __syncthreads();
        sd[t] += v;
        __syncthreads();
    }
    if (t < NBE) H[t * NB + j] = bucketBase[j] + sd[t] - val;
}

// ---------- scatter into bucket regions (LDS cursors, no global atomics) ----------
__global__ __launch_bounds__(512) void k_scatter(const int* __restrict__ ei,
                                                 const float* __restrict__ w,
                                                 const int* __restrict__ blockBase,
                                                 int2* __restrict__ rec) {
    __shared__ int bases[NB];
    __shared__ int cur[NB];
    int t = threadIdx.x, b = blockIdx.x;
    for (int i = t; i < NB; i += 512) { bases[i] = blockBase[b * NB + i]; cur[i] = 0; }
    __syncthreads();
    int base = b * EB;
    for (int i = t; i < EB; i += 512) {
        int e = base + i;
        if (e < N_EDGES) {
            int s = ei[e], d = ei[N_EDGES + e];
            float wv = w[e];
            int bin = d >> 8;
            int pos = bases[bin] + atomicAdd(&cur[bin], 1);
            rec[pos] = make_int2(s | ((d & 255) << 17), __float_as_int(wv));
        }
    }
}

// ---------- per-bucket counting sort by local dst + deg/dinv; payload = w*dinv[dst] ----------
__global__ __launch_bounds__(512) void k_bsort(const int* __restrict__ bucketBase,
                                               const int2* __restrict__ rec,
                                               int2* __restrict__ rec2,
                                               float* __restrict__ dinv,
                                               int* __restrict__ rowStart) {
    __shared__ int   cnt[256];
    __shared__ float wsum[256];   // w sums, then reused as local dinv
    __shared__ int   cur[256];
    __shared__ int   sd[512];
    int t = threadIdx.x, b = blockIdx.x;
    if (t < 256) { cnt[t] = 0; wsum[t] = 0.f; }
    __syncthreads();
    int r0 = bucketBase[b], r1 = bucketBase[b + 1];
    for (int i = r0 + t; i < r1; i += 512) {
        int2 rv = rec[i];
        int l = (rv.x >> 17) & 255;
        atomicAdd(&cnt[l], 1);
        atomicAdd(&wsum[l], __int_as_float(rv.y));
    }
    __syncthreads();
    int val = (t < 256) ? cnt[t] : 0;
    sd[t] = val;
    __syncthreads();
    for (int off = 1; off < 512; off <<= 1) {
        int v = (t >= off) ? sd[t - off] : 0;
        __syncthreads();
        sd[t] += v;
        __syncthreads();
    }
    float dloc = 0.f;
    if (t < 256) {
        int excl = sd[t] - val;
        cur[t] = excl;
        int node = b * BSZ + t;
        dloc = rsqrtf(1.f + wsum[t]);
        if (node < N_NODES) {
            rowStart[node] = r0 + excl;
            dinv[node] = dloc;
        }
    }
    __syncthreads();
    if (t < 256) wsum[t] = dloc;   // reuse as local dinv
    __syncthreads();
    for (int i = r0 + t; i < r1; i += 512) {
        int2 rv = rec[i];
        int l = (rv.x >> 17) & 255;
        float cpart = __int_as_float(rv.y) * wsum[l];   // w * dinv[dst]
        int pos = r0 + atomicAdd(&cur[l], 1);
        rec2[pos] = make_int2(rv.x & 0x1FFFF, __float_as_int(cpart));
    }
}

// ---------- h1' = (x @ W1) * dinv[row], stored bf16 ----------
__global__ __launch_bounds__(256) void k_mm1(const float* __restrict__ x,
                                             const float* __restrict__ W1,
                                             const float* __restrict__ dinv,
                                             unsigned short* __restrict__ h1p) {
    int t = threadIdx.x, lane = t & 63, wv = t >> 6;
    int wid = blockIdx.x * 4 + wv, nw = gridDim.x * 4;
    float Wc[64];
#pragma unroll
    for (int k = 0; k < 64; ++k) Wc[k] = W1[k * 64 + lane];
    for (int r0 = wid * 4; r0 < N_NODES; r0 += nw * 4) {
        float x0 = x[(r0 + 0) * 64 + lane];
        float x1 = x[(r0 + 1) * 64 + lane];
        float x2 = x[(r0 + 2) * 64 + lane];
        float x3 = x[(r0 + 3) * 64 + lane];
        float d0 = dinv[r0 + 0], d1 = dinv[r0 + 1], d2 = dinv[r0 + 2], d3 = dinv[r0 + 3];
        float a0 = 0.f, a1 = 0.f, a2 = 0.f, a3 = 0.f;
#pragma unroll
        for (int k = 0; k < 64; ++k) {
            float wk = Wc[k];
            a0 = fmaf(rlane(x0, k), wk, a0);
            a1 = fmaf(rlane(x1, k), wk, a1);
            a2 = fmaf(rlane(x2, k), wk, a2);
            a3 = fmaf(rlane(x3, k), wk, a3);
        }
        h1p[(r0 + 0) * 64 + lane] = f2bf(a0 * d0);
        h1p[(r0 + 1) * 64 + lane] = f2bf(a1 * d1);
        h1p[(r0 + 2) * 64 + lane] = f2bf(a2 * d2);
        h1p[(r0 + 3) * 64 + lane] = f2bf(a3 * d3);
    }
}

// ---------- agg1 + relu/bias + mm2 fused: h2' = (relu(agg+b1)@W2)*dinv, bf16 ----------
// Scalar-record gather loop: node is wave-uniform (readfirstlane) so rec2[j]
// becomes s_load and the row gather is one global_load_ushort per edge.
__global__ __launch_bounds__(256) void k_agg1f(const int* __restrict__ rowStart,
                                               const int2* __restrict__ rec2,
                                               const float* __restrict__ dinv,
                                               const unsigned short* __restrict__ h1p,
                                               const float* __restrict__ b1,
                                               const float* __restrict__ W2,
                                               unsigned short* __restrict__ h2p) {
    int t = threadIdx.x, lane = t & 63;
    int node = __builtin_amdgcn_readfirstlane(blockIdx.x * 4 + (t >> 6));
    if (node >= N_NODES) return;
    bool act = lane < C_DIM;
    float Wc[64];
#pragma unroll
    for (int k = 0; k < 64; ++k) Wc[k] = act ? W2[k * C_DIM + lane] : 0.f;
    float bv = b1[lane];
    float dn = dinv[node];
    float acc = bf2f(h1p[node * 64 + lane]) * dn;  // self loop: h1'*dinv
    int s0 = rowStart[node], s1 = rowStart[node + 1];
#pragma unroll 4
    for (int j = s0; j < s1; ++j) {
        int2 ev = rec2[j];                               // scalar load
        acc = fmaf(bf2f(h1p[ev.x * 64 + lane]), __int_as_float(ev.y), acc);
    }
    // fused relu + bias + @W2 (readlane broadcast) + *dinv
    float r = fmaxf(acc + bv, 0.f);
    float o = 0.f;
#pragma unroll
    for (int k = 0; k < 64; ++k) o = fmaf(rlane(r, k), Wc[k], o);
    if (act) h2p[node * C_DIM + lane] = f2bf(o * dn);
}

// ---------- agg2 + self-loop + bias + log_softmax fused, scalar-record loop ----------
__global__ __launch_bounds__(256) void k_agg2(const int* __restrict__ rowStart,
                                              const int2* __restrict__ rec2,
                                              const float* __restrict__ dinv,
                                              const unsigned short* __restrict__ h2p,
                                              const float* __restrict__ b2,
                                              float* __restrict__ out) {
    int t = threadIdx.x, lane = t & 63;
    int node = __builtin_amdgcn_readfirstlane(blockIdx.x * 4 + (t >> 6));
    if (node >= N_NODES) return;
    bool act = lane < C_DIM;
    float dn = dinv[node];
    float acc = act ? bf2f(h2p[node * C_DIM + lane]) * dn : 0.f;  // self loop
    int s0 = rowStart[node], s1 = rowStart[node + 1];
#pragma unroll 4
    for (int j = s0; j < s1; ++j) {
        int2 ev = rec2[j];                               // scalar load
        float hv = act ? bf2f(h2p[ev.x * C_DIM + lane]) : 0.f;
        acc = fmaf(hv, __int_as_float(ev.y), acc);
    }
    float v = act ? acc + b2[lane] : -INFINITY;
    float m = v;
#pragma unroll
    for (int off = 32; off; off >>= 1) m = fmaxf(m, __shfl_xor(m, off, 64));
    float ex = act ? expf(v - m) : 0.f;
    float s = ex;
#pragma unroll
    for (int off = 32; off; off >>= 1) s += __shfl_xor(s, off, 64);
    if (act) out[node * C_DIM + lane] = v - m - logf(s);
}

extern "C" void kernel_launch(void* const* d_in, const int* in_sizes, int n_in,
                              void* d_out, int out_size, void* d_ws, size_t ws_size,
                              hipStream_t stream) {
    const float* x  = (const float*)d_in[0];
    const int*   ei = (const int*)d_in[1];
    const float* w  = (const float*)d_in[2];
    const float* W1 = (const float*)d_in[3];
    const float* b1 = (const float*)d_in[4];
    const float* W2 = (const float*)d_in[5];
    const float* b2 = (const float*)d_in[6];
    float* out = (float*)d_out;

    float* wsf = (float*)d_ws;
    int*   wsi = (int*)d_ws;
    float* dinv       = wsf + OFF_DINV;
    int*   bucketBase = wsi + OFF_BB;
    int*   rowStart   = wsi + OFF_ROW;
    int*   H          = wsi + OFF_H;
    int2*  rec2       = (int2*)(wsi + OFF_REC2);
    int2*  rec        = (int2*)(wsi + OFF_H1P);              // dead before h1p written
    unsigned short* h1p = (unsigned short*)(wsi + OFF_H1P);
    unsigned short* h2p = (unsigned short*)(wsi + OFF_H2P);
    float* agg1 = nullptr; (void)agg1;

    // CSR build — zero global atomics
    k_hist2d<<<NBE, 512, 0, stream>>>(ei, H);
    k_bucketsum<<<1, 512, 0, stream>>>(H, bucketBase, rowStart);
    k_colscan<<<NB, 512, 0, stream>>>(H, bucketBase);
    k_scatter<<<NBE, 512, 0, stream>>>(ei, w, H, rec);
    k_bsort<<<NB, 512, 0, stream>>>(bucketBase, rec, rec2, dinv, rowStart);

    // layer 1 + fused layer-2 linear
    k_mm1<<<512, 256, 0, stream>>>(x, W1, dinv, h1p);
    k_agg1f<<<(N_NODES + 3) / 4, 256, 0, stream>>>(rowStart, rec2, dinv, h1p, b1, W2, h2p);

    // layer-2 aggregation + bias + log-softmax
    k_agg2<<<(N_NODES + 3) / 4, 256, 0, stream>>>(rowStart, rec2, dinv, h2p, b2, out);
}

// Round 7
// 345.603 us; speedup vs baseline: 1.1451x; 1.1451x over previous
//
#include <hip/hip_runtime.h>
#include <math.h>

#define N_NODES 100000
#define N_EDGES 1600000
#define C_DIM 40

#define BSZ 256                           // nodes per bucket
#define NB  ((N_NODES + BSZ - 1) / BSZ)   // 391
#define EB  4096                          // edges per hist/scatter block
#define NBE ((N_EDGES + EB - 1) / EB)     // 391

// ---------------- workspace layout (4-byte units) ----------------
#define OFF_DINV 0                        // float[100000]
#define OFF_BB   100000                   // int[NB+1]
#define OFF_CS   100392                   // int[NB] column sums
#define OFF_ROW  100800                   // int[N+1]
#define OFF_H    200802                   // int[NBE*NB]
#define OFF_REC2 353684                   // int2[E] sorted records (even -> 8B aligned)
#define OFF_H1P  3553684                  // ushort[N*64] bf16 h1'; unsorted rec aliases here
#define OFF_H2P  6753684                  // ushort[N*40] bf16 h2'
// total ~8.75M ints = 35 MB

__device__ inline float rlane(float v, int k) {
    return __int_as_float(__builtin_amdgcn_readlane(__float_as_int(v), k));
}
__device__ inline unsigned short f2bf(float f) {
    unsigned int u = __float_as_uint(f);
    u += 0x7FFF + ((u >> 16) & 1);        // round to nearest even
    return (unsigned short)(u >> 16);
}
__device__ inline float bf2f(unsigned short h) {
    return __uint_as_float(((unsigned int)h) << 16);
}

// ---------- per-block bucket histogram: H[b][j] + global column sums ----------
__global__ __launch_bounds__(512) void k_hist2d(const int* __restrict__ ei,
                                                int* __restrict__ H,
                                                int* __restrict__ colsum) {
    __shared__ int bins[NB];
    int t = threadIdx.x, b = blockIdx.x;
    for (int i = t; i < NB; i += 512) bins[i] = 0;
    __syncthreads();
    int base = b * EB;
    for (int i = t; i < EB; i += 512) {
        int e = base + i;
        if (e < N_EDGES) atomicAdd(&bins[ei[N_EDGES + e] >> 8], 1);
    }
    __syncthreads();
    for (int i = t; i < NB; i += 512) {
        int c = bins[i];
        H[b * NB + i] = c;
        if (c) atomicAdd(&colsum[i], c);
    }
}

// ---------- bucketBase = exclusive scan of colsum (1 block, tiny) ----------
__global__ __launch_bounds__(512) void k_bucketsum(const int* __restrict__ colsum,
                                                   int* __restrict__ bucketBase,
                                                   int* __restrict__ rowStart) {
    __shared__ int sd[512];
    int t = threadIdx.x;
    int val = (t < NB) ? colsum[t] : 0;
    sd[t] = val;
    __syncthreads();
    for (int off = 1; off < 512; off <<= 1) {
        int v = (t >= off) ? sd[t - off] : 0;
        __syncthreads();
        sd[t] += v;
        __syncthreads();
    }
    if (t < NB) bucketBase[t] = sd[t] - val;
    if (t == NB - 1) bucketBase[NB] = sd[t];
    if (t == 0) rowStart[N_NODES] = N_EDGES;
}

// ---------- column scan: H[b][j] -> bucketBase[j] + prefix_b (in place) ----------
__global__ __launch_bounds__(512) void k_colscan(int* __restrict__ H,
                                                 const int* __restrict__ bucketBase) {
    __shared__ int sd[512];
    int t = threadIdx.x, j = blockIdx.x;
    int val = (t < NBE) ? H[t * NB + j] : 0;
    sd[t] = val;
    __syncthreads();
    for (int off = 1; off < 512; off <<= 1) {
        int v = (t >= off) ? sd[t - off] : 0;
        __syncthreads();
        sd[t] += v;
        __syncthreads();
    }
    if (t < NBE) H[t * NB + j] = bucketBase[j] + sd[t] - val;
}

// ---------- scatter into bucket regions (LDS cursors, no global atomics) ----------
__global__ __launch_bounds__(512) void k_scatter(const int* __restrict__ ei,
                                                 const float* __restrict__ w,
                                                 const int* __restrict__ blockBase,
                                                 int2* __restrict__ rec) {
    __shared__ int bases[NB];
    __shared__ int cur[NB];
    int t = threadIdx.x, b = blockIdx.x;
    for (int i = t; i < NB; i += 512) { bases[i] = blockBase[b * NB + i]; cur[i] = 0; }
    __syncthreads();
    int base = b * EB;
    for (int i = t; i < EB; i += 512) {
        int e = base + i;
        if (e < N_EDGES) {
            int s = ei[e], d = ei[N_EDGES + e];
            float wv = w[e];
            int bin = d >> 8;
            int pos = bases[bin] + atomicAdd(&cur[bin], 1);
            rec[pos] = make_int2(s | ((d & 255) << 17), __float_as_int(wv));
        }
    }
}

// ---------- per-bucket counting sort by local dst + deg/dinv; payload = w*dinv[dst] ----------
__global__ __launch_bounds__(512) void k_bsort(const int* __restrict__ bucketBase,
                                               const int2* __restrict__ rec,
                                               int2* __restrict__ rec2,
                                               float* __restrict__ dinv,
                                               int* __restrict__ rowStart) {
    __shared__ int   cnt[256];
    __shared__ float wsum[256];   // w sums, then reused as local dinv
    __shared__ int   cur[256];
    __shared__ int   sd[512];
    int t = threadIdx.x, b = blockIdx.x;
    if (t < 256) { cnt[t] = 0; wsum[t] = 0.f; }
    __syncthreads();
    int r0 = bucketBase[b], r1 = bucketBase[b + 1];
    for (int i = r0 + t; i < r1; i += 512) {
        int2 rv = rec[i];
        int l = (rv.x >> 17) & 255;
        atomicAdd(&cnt[l], 1);
        atomicAdd(&wsum[l], __int_as_float(rv.y));
    }
    __syncthreads();
    int val = (t < 256) ? cnt[t] : 0;
    sd[t] = val;
    __syncthreads();
    for (int off = 1; off < 512; off <<= 1) {
        int v = (t >= off) ? sd[t - off] : 0;
        __syncthreads();
        sd[t] += v;
        __syncthreads();
    }
    float dloc = 0.f;
    if (t < 256) {
        int excl = sd[t] - val;
        cur[t] = excl;
        int node = b * BSZ + t;
        dloc = rsqrtf(1.f + wsum[t]);
        if (node < N_NODES) {
            rowStart[node] = r0 + excl;
            dinv[node] = dloc;
        }
    }
    __syncthreads();
    if (t < 256) wsum[t] = dloc;   // reuse as local dinv
    __syncthreads();
    for (int i = r0 + t; i < r1; i += 512) {
        int2 rv = rec[i];
        int l = (rv.x >> 17) & 255;
        float cpart = __int_as_float(rv.y) * wsum[l];   // w * dinv[dst]
        int pos = r0 + atomicAdd(&cur[l], 1);
        rec2[pos] = make_int2(rv.x & 0x1FFFF, __float_as_int(cpart));
    }
}

// ---------- h1' = (x @ W1) * dinv[row], stored bf16 ----------
__global__ __launch_bounds__(256) void k_mm1(const float* __restrict__ x,
                                             const float* __restrict__ W1,
                                             const float* __restrict__ dinv,
                                             unsigned short* __restrict__ h1p) {
    int t = threadIdx.x, lane = t & 63, wv = t >> 6;
    int wid = blockIdx.x * 4 + wv, nw = gridDim.x * 4;
    float Wc[64];
#pragma unroll
    for (int k = 0; k < 64; ++k) Wc[k] = W1[k * 64 + lane];
    for (int r0 = wid * 4; r0 < N_NODES; r0 += nw * 4) {
        float x0 = x[(r0 + 0) * 64 + lane];
        float x1 = x[(r0 + 1) * 64 + lane];
        float x2 = x[(r0 + 2) * 64 + lane];
        float x3 = x[(r0 + 3) * 64 + lane];
        float d0 = dinv[r0 + 0], d1 = dinv[r0 + 1], d2 = dinv[r0 + 2], d3 = dinv[r0 + 3];
        float a0 = 0.f, a1 = 0.f, a2 = 0.f, a3 = 0.f;
#pragma unroll
        for (int k = 0; k < 64; ++k) {
            float wk = Wc[k];
            a0 = fmaf(rlane(x0, k), wk, a0);
            a1 = fmaf(rlane(x1, k), wk, a1);
            a2 = fmaf(rlane(x2, k), wk, a2);
            a3 = fmaf(rlane(x3, k), wk, a3);
        }
        h1p[(r0 + 0) * 64 + lane] = f2bf(a0 * d0);
        h1p[(r0 + 1) * 64 + lane] = f2bf(a1 * d1);
        h1p[(r0 + 2) * 64 + lane] = f2bf(a2 * d2);
        h1p[(r0 + 3) * 64 + lane] = f2bf(a3 * d3);
    }
}

// ---------- agg1: CSR gather, lane-parallel records + shuffle bcast, 4 accs ----------
__global__ __launch_bounds__(256) void k_agg1(const int* __restrict__ rowStart,
                                              const int2* __restrict__ rec2,
                                              const float* __restrict__ dinv,
                                              const unsigned short* __restrict__ h1p,
                                              float* __restrict__ agg1) {
    int t = threadIdx.x, lane = t & 63;
    int node = blockIdx.x * 4 + (t >> 6);
    if (node >= N_NODES) return;
    float dn = dinv[node];
    float acc0 = bf2f(h1p[node * 64 + lane]) * dn;  // self loop: h1'*dinv
    float acc1 = 0.f, acc2 = 0.f, acc3 = 0.f;
    int s0 = rowStart[node], s1 = rowStart[node + 1];
    for (int base = s0; base < s1; base += 64) {
        int idx = base + lane;
        int2 ev = (idx < s1) ? rec2[idx] : make_int2(0, 0);
        int cnt = min(64, s1 - base);
        int j = 0;
        for (; j + 3 < cnt; j += 4) {
            int   i0 = __shfl(ev.x, j, 64),     i1 = __shfl(ev.x, j + 1, 64);
            int   i2 = __shfl(ev.x, j + 2, 64), i3 = __shfl(ev.x, j + 3, 64);
            float c0 = __int_as_float(__shfl(ev.y, j, 64));
            float c1 = __int_as_float(__shfl(ev.y, j + 1, 64));
            float c2 = __int_as_float(__shfl(ev.y, j + 2, 64));
            float c3 = __int_as_float(__shfl(ev.y, j + 3, 64));
            float v0 = bf2f(h1p[i0 * 64 + lane]), v1 = bf2f(h1p[i1 * 64 + lane]);
            float v2 = bf2f(h1p[i2 * 64 + lane]), v3 = bf2f(h1p[i3 * 64 + lane]);
            acc0 = fmaf(v0, c0, acc0);
            acc1 = fmaf(v1, c1, acc1);
            acc2 = fmaf(v2, c2, acc2);
            acc3 = fmaf(v3, c3, acc3);
        }
        for (; j < cnt; ++j) {
            int ss = __shfl(ev.x, j, 64);
            float cc = __int_as_float(__shfl(ev.y, j, 64));
            acc0 = fmaf(bf2f(h1p[ss * 64 + lane]), cc, acc0);
        }
    }
    agg1[node * 64 + lane] = (acc0 + acc1) + (acc2 + acc3);
}

// ---------- h2' = (relu(agg1+b1) @ W2) * dinv[row], stored bf16 ----------
__global__ __launch_bounds__(256) void k_mm2(const float* __restrict__ agg1,
                                             const float* __restrict__ b1,
                                             const float* __restrict__ W2,
                                             const float* __restrict__ dinv,
                                             unsigned short* __restrict__ h2p) {
    int t = threadIdx.x, lane = t & 63, wv = t >> 6;
    int wid = blockIdx.x * 4 + wv, nw = gridDim.x * 4;
    bool act = lane < C_DIM;
    float Wc[64];
#pragma unroll
    for (int k = 0; k < 64; ++k) Wc[k] = act ? W2[k * C_DIM + lane] : 0.f;
    float bv = b1[lane];
    for (int r0 = wid * 4; r0 < N_NODES; r0 += nw * 4) {
        float x0 = fmaxf(agg1[(r0 + 0) * 64 + lane] + bv, 0.f);
        float x1 = fmaxf(agg1[(r0 + 1) * 64 + lane] + bv, 0.f);
        float x2 = fmaxf(agg1[(r0 + 2) * 64 + lane] + bv, 0.f);
        float x3 = fmaxf(agg1[(r0 + 3) * 64 + lane] + bv, 0.f);
        float d0 = dinv[r0 + 0], d1 = dinv[r0 + 1], d2 = dinv[r0 + 2], d3 = dinv[r0 + 3];
        float a0 = 0.f, a1 = 0.f, a2 = 0.f, a3 = 0.f;
#pragma unroll
        for (int k = 0; k < 64; ++k) {
            float wk = Wc[k];
            a0 = fmaf(rlane(x0, k), wk, a0);
            a1 = fmaf(rlane(x1, k), wk, a1);
            a2 = fmaf(rlane(x2, k), wk, a2);
            a3 = fmaf(rlane(x3, k), wk, a3);
        }
        if (act) {
            h2p[(r0 + 0) * C_DIM + lane] = f2bf(a0 * d0);
            h2p[(r0 + 1) * C_DIM + lane] = f2bf(a1 * d1);
            h2p[(r0 + 2) * C_DIM + lane] = f2bf(a2 * d2);
            h2p[(r0 + 3) * C_DIM + lane] = f2bf(a3 * d3);
        }
    }
}

// ---------- agg2 + self-loop + bias + log_softmax fused, 4 accs ----------
__global__ __launch_bounds__(256) void k_agg2(const int* __restrict__ rowStart,
                                              const int2* __restrict__ rec2,
                                              const float* __restrict__ dinv,
                                              const unsigned short* __restrict__ h2p,
                                              const float* __restrict__ b2,
                                              float* __restrict__ out) {
    int t = threadIdx.x, lane = t & 63;
    int node = blockIdx.x * 4 + (t >> 6);
    if (node >= N_NODES) return;
    bool act = lane < C_DIM;
    float dn = dinv[node];
    float acc0 = act ? bf2f(h2p[node * C_DIM + lane]) * dn : 0.f;  // self loop
    float acc1 = 0.f, acc2 = 0.f, acc3 = 0.f;
    int s0 = rowStart[node], s1 = rowStart[node + 1];
    for (int base = s0; base < s1; base += 64) {
        int idx = base + lane;
        int2 ev = (idx < s1) ? rec2[idx] : make_int2(0, 0);
        int cnt = min(64, s1 - base);
        int j = 0;
        for (; j + 3 < cnt; j += 4) {
            int   i0 = __shfl(ev.x, j, 64),     i1 = __shfl(ev.x, j + 1, 64);
            int   i2 = __shfl(ev.x, j + 2, 64), i3 = __shfl(ev.x, j + 3, 64);
            float c0 = __int_as_float(__shfl(ev.y, j, 64));
            float c1 = __int_as_float(__shfl(ev.y, j + 1, 64));
            float c2 = __int_as_float(__shfl(ev.y, j + 2, 64));
            float c3 = __int_as_float(__shfl(ev.y, j + 3, 64));
            if (act) {
                float v0 = bf2f(h2p[i0 * C_DIM + lane]), v1 = bf2f(h2p[i1 * C_DIM + lane]);
                float v2 = bf2f(h2p[i2 * C_DIM + lane]), v3 = bf2f(h2p[i3 * C_DIM + lane]);
                acc0 = fmaf(v0, c0, acc0);
                acc1 = fmaf(v1, c1, acc1);
                acc2 = fmaf(v2, c2, acc2);
                acc3 = fmaf(v3, c3, acc3);
            }
        }
        for (; j < cnt; ++j) {
            int ss = __shfl(ev.x, j, 64);
            float cc = __int_as_float(__shfl(ev.y, j, 64));
            if (act) acc0 = fmaf(bf2f(h2p[ss * C_DIM + lane]), cc, acc0);
        }
    }
    float acc = (acc0 + acc1) + (acc2 + acc3);
    float v = act ? acc + b2[lane] : -INFINITY;
    float m = v;
#pragma unroll
    for (int off = 32; off; off >>= 1) m = fmaxf(m, __shfl_xor(m, off, 64));
    float ex = act ? expf(v - m) : 0.f;
    float s = ex;
#pragma unroll
    for (int off = 32; off; off >>= 1) s += __shfl_xor(s, off, 64);
    if (act) out[node * C_DIM + lane] = v - m - logf(s);
}

extern "C" void kernel_launch(void* const* d_in, const int* in_sizes, int n_in,
                              void* d_out, int out_size, void* d_ws, size_t ws_size,
                              hipStream_t stream) {
    const float* x  = (const float*)d_in[0];
    const int*   ei = (const int*)d_in[1];
    const float* w  = (const float*)d_in[2];
    const float* W1 = (const float*)d_in[3];
    const float* b1 = (const float*)d_in[4];
    const float* W2 = (const float*)d_in[5];
    const float* b2 = (const float*)d_in[6];
    float* out = (float*)d_out;

    float* wsf = (float*)d_ws;
    int*   wsi = (int*)d_ws;
    float* dinv       = wsf + OFF_DINV;
    int*   bucketBase = wsi + OFF_BB;
    int*   colsum     = wsi + OFF_CS;
    int*   rowStart   = wsi + OFF_ROW;
    int*   H          = wsi + OFF_H;
    int2*  rec2       = (int2*)(wsi + OFF_REC2);
    int2*  rec        = (int2*)(wsi + OFF_H1P);              // dead before h1p written
    unsigned short* h1p = (unsigned short*)(wsi + OFF_H1P);
    unsigned short* h2p = (unsigned short*)(wsi + OFF_H2P);
    float* agg1       = wsf + OFF_H2P;  // NOTE: agg1 fp32 reuses... (see below)

    // agg1 needs its own fp32 region: place it after h2p
    float* agg1f = wsf + 8753684 / 1;   // int offset == float offset
    agg1 = agg1f;

    // CSR build — zero global atomics except 391-bin colsum
    hipMemsetAsync(colsum, 0, NB * sizeof(int), stream);
    k_hist2d<<<NBE, 512, 0, stream>>>(ei, H, colsum);
    k_bucketsum<<<1, 512, 0, stream>>>(colsum, bucketBase, rowStart);
    k_colscan<<<NB, 512, 0, stream>>>(H, bucketBase);
    k_scatter<<<NBE, 512, 0, stream>>>(ei, w, H, rec);
    k_bsort<<<NB, 512, 0, stream>>>(bucketBase, rec, rec2, dinv, rowStart);

    // layer 1
    k_mm1<<<512, 256, 0, stream>>>(x, W1, dinv, h1p);
    k_agg1<<<(N_NODES + 3) / 4, 256, 0, stream>>>(rowStart, rec2, dinv, h1p, agg1);

    // layer 2 (+ fused bias/log-softmax epilogue)
    k_mm2<<<512, 256, 0, stream>>>(agg1, b1, W2, dinv, h2p);
    k_agg2<<<(N_NODES + 3) / 4, 256, 0, stream>>>(rowStart, rec2, dinv, h2p, b2, out);
}

// Round 8
// 337.742 us; speedup vs baseline: 1.1717x; 1.0233x over previous
//
#include <hip/hip_runtime.h>
#include <math.h>

#define N_NODES 100000
#define N_EDGES 1600000
#define C_DIM 40

#define BSZ 256                           // nodes per bucket
#define NB  ((N_NODES + BSZ - 1) / BSZ)   // 391
#define EB  4096                          // edges per hist/scatter block
#define NBE ((N_EDGES + EB - 1) / EB)     // 391

// ---------------- workspace layout (4-byte units) ----------------
#define OFF_DINV 0                        // float[100000]
#define OFF_BB   100000                   // int[NB+1]
#define OFF_CS   100392                   // int[NB] column sums
#define OFF_ROW  100800                   // int[N+1]
#define OFF_H    200802                   // int[NBE*NB]
#define OFF_REC2 353684                   // int2[E] sorted records (even -> 8B aligned)
#define OFF_H1P  3553684                  // ushort[N*64] bf16 h1'; unsorted rec aliases here
#define OFF_H2P  6753684                  // ushort[N*64] bf16 h2' (padded to 128B rows)
#define OFF_AGG1 9953684                  // float[N*64]
// total ~16.35M ints = 65.4 MB

__device__ inline float rlane(float v, int k) {
    return __int_as_float(__builtin_amdgcn_readlane(__float_as_int(v), k));
}
__device__ inline unsigned short f2bf(float f) {
    unsigned int u = __float_as_uint(f);
    u += 0x7FFF + ((u >> 16) & 1);        // round to nearest even
    return (unsigned short)(u >> 16);
}
__device__ inline float bf2f(unsigned short h) {
    return __uint_as_float(((unsigned int)h) << 16);
}

// ---------- per-block bucket histogram: H[b][j] + global column sums ----------
__global__ __launch_bounds__(512) void k_hist2d(const int* __restrict__ ei,
                                                int* __restrict__ H,
                                                int* __restrict__ colsum) {
    __shared__ int bins[NB];
    int t = threadIdx.x, b = blockIdx.x;
    for (int i = t; i < NB; i += 512) bins[i] = 0;
    __syncthreads();
    int base = b * EB;
    for (int i = t; i < EB; i += 512) {
        int e = base + i;
        if (e < N_EDGES) atomicAdd(&bins[ei[N_EDGES + e] >> 8], 1);
    }
    __syncthreads();
    for (int i = t; i < NB; i += 512) {
        int c = bins[i];
        H[b * NB + i] = c;
        if (c) atomicAdd(&colsum[i], c);
    }
}

// ---------- column scan (self-computes bucketBase[j] from colsum) ----------
__global__ __launch_bounds__(512) void k_colscan(int* __restrict__ H,
                                                 const int* __restrict__ colsum,
                                                 int* __restrict__ bucketBase,
                                                 int* __restrict__ rowStart) {
    __shared__ int sd[512];
    __shared__ int sbase;
    int t = threadIdx.x, j = blockIdx.x;
    // base_j = sum colsum[0..j-1]
    int p = 0;
    for (int i = t; i < j; i += 512) p += colsum[i];
    sd[t] = p;
    __syncthreads();
    for (int off = 256; off > 0; off >>= 1) {
        if (t < off) sd[t] += sd[t + off];
        __syncthreads();
    }
    if (t == 0) sbase = sd[0];
    __syncthreads();
    int base = sbase;
    if (t == 0) {
        bucketBase[j] = base;
        if (j == NB - 1) { bucketBase[NB] = base + colsum[j]; rowStart[N_NODES] = N_EDGES; }
    }
    __syncthreads();
    // exclusive scan down the column, offset by base (in place)
    int val = (t < NBE) ? H[t * NB + j] : 0;
    sd[t] = val;
    __syncthreads();
    for (int off = 1; off < 512; off <<= 1) {
        int v = (t >= off) ? sd[t - off] : 0;
        __syncthreads();
        sd[t] += v;
        __syncthreads();
    }
    if (t < NBE) H[t * NB + j] = base + sd[t] - val;
}

// ---------- scatter into bucket regions (LDS cursors, no global atomics) ----------
__global__ __launch_bounds__(512) void k_scatter(const int* __restrict__ ei,
                                                 const float* __restrict__ w,
                                                 const int* __restrict__ blockBase,
                                                 int2* __restrict__ rec) {
    __shared__ int bases[NB];
    __shared__ int cur[NB];
    int t = threadIdx.x, b = blockIdx.x;
    for (int i = t; i < NB; i += 512) { bases[i] = blockBase[b * NB + i]; cur[i] = 0; }
    __syncthreads();
    int base = b * EB;
    for (int i = t; i < EB; i += 512) {
        int e = base + i;
        if (e < N_EDGES) {
            int s = ei[e], d = ei[N_EDGES + e];
            float wv = w[e];
            int bin = d >> 8;
            int pos = bases[bin] + atomicAdd(&cur[bin], 1);
            rec[pos] = make_int2(s | ((d & 255) << 17), __float_as_int(wv));
        }
    }
}

// ---------- per-bucket counting sort; payload = w*dinv[dst]; x = src byte-offset ----------
__global__ __launch_bounds__(512) void k_bsort(const int* __restrict__ bucketBase,
                                               const int2* __restrict__ rec,
                                               int2* __restrict__ rec2,
                                               float* __restrict__ dinv,
                                               int* __restrict__ rowStart) {
    __shared__ int   cnt[256];
    __shared__ float wsum[256];   // w sums, then reused as local dinv
    __shared__ int   cur[256];
    __shared__ int   sd[512];
    int t = threadIdx.x, b = blockIdx.x;
    if (t < 256) { cnt[t] = 0; wsum[t] = 0.f; }
    __syncthreads();
    int r0 = bucketBase[b], r1 = bucketBase[b + 1];
    for (int i = r0 + t; i < r1; i += 512) {
        int2 rv = rec[i];
        int l = (rv.x >> 17) & 255;
        atomicAdd(&cnt[l], 1);
        atomicAdd(&wsum[l], __int_as_float(rv.y));
    }
    __syncthreads();
    int val = (t < 256) ? cnt[t] : 0;
    sd[t] = val;
    __syncthreads();
    for (int off = 1; off < 512; off <<= 1) {
        int v = (t >= off) ? sd[t - off] : 0;
        __syncthreads();
        sd[t] += v;
        __syncthreads();
    }
    float dloc = 0.f;
    if (t < 256) {
        int excl = sd[t] - val;
        cur[t] = excl;
        int node = b * BSZ + t;
        dloc = rsqrtf(1.f + wsum[t]);
        if (node < N_NODES) {
            rowStart[node] = r0 + excl;
            dinv[node] = dloc;
        }
    }
    __syncthreads();
    if (t < 256) wsum[t] = dloc;   // reuse as local dinv
    __syncthreads();
    for (int i = r0 + t; i < r1; i += 512) {
        int2 rv = rec[i];
        int l = (rv.x >> 17) & 255;
        float cpart = __int_as_float(rv.y) * wsum[l];   // w * dinv[dst]
        int pos = r0 + atomicAdd(&cur[l], 1);
        rec2[pos] = make_int2((rv.x & 0x1FFFF) << 7, __float_as_int(cpart));  // src*128B
    }
}

// ---------- h1' = (x @ W1) * dinv[row], stored bf16 ----------
__global__ __launch_bounds__(256) void k_mm1(const float* __restrict__ x,
                                             const float* __restrict__ W1,
                                             const float* __restrict__ dinv,
                                             unsigned short* __restrict__ h1p) {
    int t = threadIdx.x, lane = t & 63, wv = t >> 6;
    int wid = blockIdx.x * 4 + wv, nw = gridDim.x * 4;
    float Wc[64];
#pragma unroll
    for (int k = 0; k < 64; ++k) Wc[k] = W1[k * 64 + lane];
    for (int r0 = wid * 4; r0 < N_NODES; r0 += nw * 4) {
        float x0 = x[(r0 + 0) * 64 + lane];
        float x1 = x[(r0 + 1) * 64 + lane];
        float x2 = x[(r0 + 2) * 64 + lane];
        float x3 = x[(r0 + 3) * 64 + lane];
        float d0 = dinv[r0 + 0], d1 = dinv[r0 + 1], d2 = dinv[r0 + 2], d3 = dinv[r0 + 3];
        float a0 = 0.f, a1 = 0.f, a2 = 0.f, a3 = 0.f;
#pragma unroll
        for (int k = 0; k < 64; ++k) {
            float wk = Wc[k];
            a0 = fmaf(rlane(x0, k), wk, a0);
            a1 = fmaf(rlane(x1, k), wk, a1);
            a2 = fmaf(rlane(x2, k), wk, a2);
            a3 = fmaf(rlane(x3, k), wk, a3);
        }
        h1p[(r0 + 0) * 64 + lane] = f2bf(a0 * d0);
        h1p[(r0 + 1) * 64 + lane] = f2bf(a1 * d1);
        h1p[(r0 + 2) * 64 + lane] = f2bf(a2 * d2);
        h1p[(r0 + 3) * 64 + lane] = f2bf(a3 * d3);
    }
}

// ---------- agg1: CSR gather; LDS-staged records, uniform ds_read broadcast ----------
__global__ __launch_bounds__(256) void k_agg1(const int* __restrict__ rowStart,
                                              const int2* __restrict__ rec2,
                                              const float* __restrict__ dinv,
                                              const unsigned short* __restrict__ h1p,
                                              float* __restrict__ agg1) {
    __shared__ int2 cache[4][64];
    int t = threadIdx.x, lane = t & 63, wv = t >> 6;
    int node = blockIdx.x * 4 + wv;
    if (node >= N_NODES) return;
    int2* wc = cache[wv];
    const char* hb = (const char*)h1p;
    int lo = lane << 1;
    float dn = dinv[node];
    float acc0 = bf2f(h1p[node * 64 + lane]) * dn;  // self loop
    float acc1 = 0.f, acc2 = 0.f, acc3 = 0.f;
    int s0 = rowStart[node], s1 = rowStart[node + 1];
    for (int base = s0; base < s1; base += 64) {
        int idx = base + lane;
        if (idx < s1) wc[lane] = rec2[idx];
        __builtin_amdgcn_wave_barrier();
        int cnt = min(64, s1 - base);
        int j = 0;
        for (; j + 3 < cnt; j += 4) {
            int2 e0 = wc[j], e1 = wc[j + 1], e2 = wc[j + 2], e3 = wc[j + 3];
            float v0 = bf2f(*(const unsigned short*)(hb + e0.x + lo));
            float v1 = bf2f(*(const unsigned short*)(hb + e1.x + lo));
            float v2 = bf2f(*(const unsigned short*)(hb + e2.x + lo));
            float v3 = bf2f(*(const unsigned short*)(hb + e3.x + lo));
            acc0 = fmaf(v0, __int_as_float(e0.y), acc0);
            acc1 = fmaf(v1, __int_as_float(e1.y), acc1);
            acc2 = fmaf(v2, __int_as_float(e2.y), acc2);
            acc3 = fmaf(v3, __int_as_float(e3.y), acc3);
        }
        for (; j < cnt; ++j) {
            int2 e0 = wc[j];
            acc0 = fmaf(bf2f(*(const unsigned short*)(hb + e0.x + lo)),
                        __int_as_float(e0.y), acc0);
        }
        __builtin_amdgcn_wave_barrier();
    }
    agg1[node * 64 + lane] = (acc0 + acc1) + (acc2 + acc3);
}

// ---------- h2' = (relu(agg1+b1) @ W2) * dinv[row], bf16, 128B-padded rows ----------
__global__ __launch_bounds__(256) void k_mm2(const float* __restrict__ agg1,
                                             const float* __restrict__ b1,
                                             const float* __restrict__ W2,
                                             const float* __restrict__ dinv,
                                             unsigned short* __restrict__ h2p) {
    int t = threadIdx.x, lane = t & 63, wv = t >> 6;
    int wid = blockIdx.x * 4 + wv, nw = gridDim.x * 4;
    bool act = lane < C_DIM;
    float Wc[64];
#pragma unroll
    for (int k = 0; k < 64; ++k) Wc[k] = act ? W2[k * C_DIM + lane] : 0.f;
    float bv = b1[lane];
    for (int r0 = wid * 4; r0 < N_NODES; r0 += nw * 4) {
        float x0 = fmaxf(agg1[(r0 + 0) * 64 + lane] + bv, 0.f);
        float x1 = fmaxf(agg1[(r0 + 1) * 64 + lane] + bv, 0.f);
        float x2 = fmaxf(agg1[(r0 + 2) * 64 + lane] + bv, 0.f);
        float x3 = fmaxf(agg1[(r0 + 3) * 64 + lane] + bv, 0.f);
        float d0 = dinv[r0 + 0], d1 = dinv[r0 + 1], d2 = dinv[r0 + 2], d3 = dinv[r0 + 3];
        float a0 = 0.f, a1 = 0.f, a2 = 0.f, a3 = 0.f;
#pragma unroll
        for (int k = 0; k < 64; ++k) {
            float wk = Wc[k];
            a0 = fmaf(rlane(x0, k), wk, a0);
            a1 = fmaf(rlane(x1, k), wk, a1);
            a2 = fmaf(rlane(x2, k), wk, a2);
            a3 = fmaf(rlane(x3, k), wk, a3);
        }
        if (act) {
            h2p[(r0 + 0) * 64 + lane] = f2bf(a0 * d0);
            h2p[(r0 + 1) * 64 + lane] = f2bf(a1 * d1);
            h2p[(r0 + 2) * 64 + lane] = f2bf(a2 * d2);
            h2p[(r0 + 3) * 64 + lane] = f2bf(a3 * d3);
        }
    }
}

// ---------- agg2 + self-loop + bias + log_softmax, LDS-staged records ----------
__global__ __launch_bounds__(256) void k_agg2(const int* __restrict__ rowStart,
                                              const int2* __restrict__ rec2,
                                              const float* __restrict__ dinv,
                                              const unsigned short* __restrict__ h2p,
                                              const float* __restrict__ b2,
                                              float* __restrict__ out) {
    __shared__ int2 cache[4][64];
    int t = threadIdx.x, lane = t & 63, wv = t >> 6;
    int node = blockIdx.x * 4 + wv;
    if (node >= N_NODES) return;
    bool act = lane < C_DIM;
    int2* wc = cache[wv];
    const char* hb = (const char*)h2p;
    int lo = lane << 1;
    float dn = dinv[node];
    float acc0 = bf2f(h2p[node * 64 + lane]) * dn;  // self loop (pad lanes: garbage, masked)
    float acc1 = 0.f, acc2 = 0.f, acc3 = 0.f;
    int s0 = rowStart[node], s1 = rowStart[node + 1];
    for (int base = s0; base < s1; base += 64) {
        int idx = base + lane;
        if (idx < s1) wc[lane] = rec2[idx];
        __builtin_amdgcn_wave_barrier();
        int cnt = min(64, s1 - base);
        int j = 0;
        for (; j + 3 < cnt; j += 4) {
            int2 e0 = wc[j], e1 = wc[j + 1], e2 = wc[j + 2], e3 = wc[j + 3];
            float v0 = bf2f(*(const unsigned short*)(hb + e0.x + lo));
            float v1 = bf2f(*(const unsigned short*)(hb + e1.x + lo));
            float v2 = bf2f(*(const unsigned short*)(hb + e2.x + lo));
            float v3 = bf2f(*(const unsigned short*)(hb + e3.x + lo));
            acc0 = fmaf(v0, __int_as_float(e0.y), acc0);
            acc1 = fmaf(v1, __int_as_float(e1.y), acc1);
            acc2 = fmaf(v2, __int_as_float(e2.y), acc2);
            acc3 = fmaf(v3, __int_as_float(e3.y), acc3);
        }
        for (; j < cnt; ++j) {
            int2 e0 = wc[j];
            acc0 = fmaf(bf2f(*(const unsigned short*)(hb + e0.x + lo)),
                        __int_as_float(e0.y), acc0);
        }
        __builtin_amdgcn_wave_barrier();
    }
    float acc = (acc0 + acc1) + (acc2 + acc3);
    float v = act ? acc + b2[lane] : -INFINITY;
    float m = v;
#pragma unroll
    for (int off = 32; off; off >>= 1) m = fmaxf(m, __shfl_xor(m, off, 64));
    float ex = act ? expf(v - m) : 0.f;
    float s = ex;
#pragma unroll
    for (int off = 32; off; off >>= 1) s += __shfl_xor(s, off, 64);
    if (act) out[node * C_DIM + lane] = v - m - logf(s);
}

extern "C" void kernel_launch(void* const* d_in, const int* in_sizes, int n_in,
                              void* d_out, int out_size, void* d_ws, size_t ws_size,
                              hipStream_t stream) {
    const float* x  = (const float*)d_in[0];
    const int*   ei = (const int*)d_in[1];
    const float* w  = (const float*)d_in[2];
    const float* W1 = (const float*)d_in[3];
    const float* b1 = (const float*)d_in[4];
    const float* W2 = (const float*)d_in[5];
    const float* b2 = (const float*)d_in[6];
    float* out = (float*)d_out;

    float* wsf = (float*)d_ws;
    int*   wsi = (int*)d_ws;
    float* dinv       = wsf + OFF_DINV;
    int*   bucketBase = wsi + OFF_BB;
    int*   colsum     = wsi + OFF_CS;
    int*   rowStart   = wsi + OFF_ROW;
    int*   H          = wsi + OFF_H;
    int2*  rec2       = (int2*)(wsi + OFF_REC2);
    int2*  rec        = (int2*)(wsi + OFF_H1P);              // dead before h1p written
    unsigned short* h1p = (unsigned short*)(wsi + OFF_H1P);
    unsigned short* h2p = (unsigned short*)(wsi + OFF_H2P);
    float* agg1       = wsf + OFF_AGG1;

    // CSR build — zero global atomics except 391-bin colsum
    hipMemsetAsync(colsum, 0, NB * sizeof(int), stream);
    k_hist2d<<<NBE, 512, 0, stream>>>(ei, H, colsum);
    k_colscan<<<NB, 512, 0, stream>>>(H, colsum, bucketBase, rowStart);
    k_scatter<<<NBE, 512, 0, stream>>>(ei, w, H, rec);
    k_bsort<<<NB, 512, 0, stream>>>(bucketBase, rec, rec2, dinv, rowStart);

    // layer 1
    k_mm1<<<512, 256, 0, stream>>>(x, W1, dinv, h1p);
    k_agg1<<<(N_NODES + 3) / 4, 256, 0, stream>>>(rowStart, rec2, dinv, h1p, agg1);

    // layer 2 (+ fused bias/log-softmax epilogue)
    k_mm2<<<512, 256, 0, stream>>>(agg1, b1, W2, dinv, h2p);
    k_agg2<<<(N_NODES + 3) / 4, 256, 0, stream>>>(rowStart, rec2, dinv, h2p, b2, out);
}

// Round 9
// 332.937 us; speedup vs baseline: 1.1887x; 1.0144x over previous
//
#include <hip/hip_runtime.h>
#include <math.h>

#define N_NODES 100000
#define N_EDGES 1600000
#define C_DIM 40

#define BSZ 256                           // nodes per bucket
#define NB  ((N_NODES + BSZ - 1) / BSZ)   // 391
#define EB  4096                          // edges per hist/scatter block
#define NBE ((N_EDGES + EB - 1) / EB)     // 391

// ---------------- workspace layout (4-byte units) ----------------
#define OFF_DINV 0                        // float[100000]
#define OFF_BB   100000                   // int[NB+1]
#define OFF_CS   100392                   // int[NB] column sums
#define OFF_ROW  100800                   // int[N+1]
#define OFF_H    200802                   // int[NBE*NB]
#define OFF_REC2 353684                   // int2[E] sorted records (even -> 8B aligned)
#define OFF_H1P  3553684                  // ushort[N*64] bf16 h1'; unsorted rec aliases here
#define OFF_H2P  6753684                  // ushort[N*64] bf16 h2' (128B padded rows)
#define OFF_AGG1 9953684                  // float[N*64]

__device__ inline float rlane(float v, int k) {
    return __int_as_float(__builtin_amdgcn_readlane(__float_as_int(v), k));
}
__device__ inline unsigned short f2bf(float f) {
    unsigned int u = __float_as_uint(f);
    u += 0x7FFF + ((u >> 16) & 1);        // round to nearest even
    return (unsigned short)(u >> 16);
}
__device__ inline float bf2f(unsigned short h) {
    return __uint_as_float(((unsigned int)h) << 16);
}
__device__ inline float bflo(unsigned int u) { return __uint_as_float(u << 16); }
__device__ inline float bfhi(unsigned int u) { return __uint_as_float(u & 0xFFFF0000u); }

// ---------- per-block bucket histogram: H[b][j] + global column sums ----------
__global__ __launch_bounds__(512) void k_hist2d(const int* __restrict__ ei,
                                                int* __restrict__ H,
                                                int* __restrict__ colsum) {
    __shared__ int bins[NB];
    int t = threadIdx.x, b = blockIdx.x;
    for (int i = t; i < NB; i += 512) bins[i] = 0;
    __syncthreads();
    int base = b * EB;
    for (int i = t; i < EB; i += 512) {
        int e = base + i;
        if (e < N_EDGES) atomicAdd(&bins[ei[N_EDGES + e] >> 8], 1);
    }
    __syncthreads();
    for (int i = t; i < NB; i += 512) {
        int c = bins[i];
        H[b * NB + i] = c;
        if (c) atomicAdd(&colsum[i], c);
    }
}

// ---------- column scan (self-computes bucketBase[j] from colsum) ----------
__global__ __launch_bounds__(512) void k_colscan(int* __restrict__ H,
                                                 const int* __restrict__ colsum,
                                                 int* __restrict__ bucketBase,
                                                 int* __restrict__ rowStart) {
    __shared__ int sd[512];
    __shared__ int sbase;
    int t = threadIdx.x, j = blockIdx.x;
    int p = 0;
    for (int i = t; i < j; i += 512) p += colsum[i];
    sd[t] = p;
    __syncthreads();
    for (int off = 256; off > 0; off >>= 1) {
        if (t < off) sd[t] += sd[t + off];
        __syncthreads();
    }
    if (t == 0) sbase = sd[0];
    __syncthreads();
    int base = sbase;
    if (t == 0) {
        bucketBase[j] = base;
        if (j == NB - 1) { bucketBase[NB] = base + colsum[j]; rowStart[N_NODES] = N_EDGES; }
    }
    __syncthreads();
    int val = (t < NBE) ? H[t * NB + j] : 0;
    sd[t] = val;
    __syncthreads();
    for (int off = 1; off < 512; off <<= 1) {
        int v = (t >= off) ? sd[t - off] : 0;
        __syncthreads();
        sd[t] += v;
        __syncthreads();
    }
    if (t < NBE) H[t * NB + j] = base + sd[t] - val;
}

// ---------- scatter into bucket regions (LDS cursors, no global atomics) ----------
__global__ __launch_bounds__(512) void k_scatter(const int* __restrict__ ei,
                                                 const float* __restrict__ w,
                                                 const int* __restrict__ blockBase,
                                                 int2* __restrict__ rec) {
    __shared__ int bases[NB];
    __shared__ int cur[NB];
    int t = threadIdx.x, b = blockIdx.x;
    for (int i = t; i < NB; i += 512) { bases[i] = blockBase[b * NB + i]; cur[i] = 0; }
    __syncthreads();
    int base = b * EB;
    for (int i = t; i < EB; i += 512) {
        int e = base + i;
        if (e < N_EDGES) {
            int s = ei[e], d = ei[N_EDGES + e];
            float wv = w[e];
            int bin = d >> 8;
            int pos = bases[bin] + atomicAdd(&cur[bin], 1);
            rec[pos] = make_int2(s | ((d & 255) << 17), __float_as_int(wv));
        }
    }
}

// ---------- per-bucket counting sort; payload = w*dinv[dst]; x = src byte-offset ----------
__global__ __launch_bounds__(512) void k_bsort(const int* __restrict__ bucketBase,
                                               const int2* __restrict__ rec,
                                               int2* __restrict__ rec2,
                                               float* __restrict__ dinv,
                                               int* __restrict__ rowStart) {
    __shared__ int   cnt[256];
    __shared__ float wsum[256];
    __shared__ int   cur[256];
    __shared__ int   sd[512];
    int t = threadIdx.x, b = blockIdx.x;
    if (t < 256) { cnt[t] = 0; wsum[t] = 0.f; }
    __syncthreads();
    int r0 = bucketBase[b], r1 = bucketBase[b + 1];
    for (int i = r0 + t; i < r1; i += 512) {
        int2 rv = rec[i];
        int l = (rv.x >> 17) & 255;
        atomicAdd(&cnt[l], 1);
        atomicAdd(&wsum[l], __int_as_float(rv.y));
    }
    __syncthreads();
    int val = (t < 256) ? cnt[t] : 0;
    sd[t] = val;
    __syncthreads();
    for (int off = 1; off < 512; off <<= 1) {
        int v = (t >= off) ? sd[t - off] : 0;
        __syncthreads();
        sd[t] += v;
        __syncthreads();
    }
    float dloc = 0.f;
    if (t < 256) {
        int excl = sd[t] - val;
        cur[t] = excl;
        int node = b * BSZ + t;
        dloc = rsqrtf(1.f + wsum[t]);
        if (node < N_NODES) {
            rowStart[node] = r0 + excl;
            dinv[node] = dloc;
        }
    }
    __syncthreads();
    if (t < 256) wsum[t] = dloc;
    __syncthreads();
    for (int i = r0 + t; i < r1; i += 512) {
        int2 rv = rec[i];
        int l = (rv.x >> 17) & 255;
        float cpart = __int_as_float(rv.y) * wsum[l];   // w * dinv[dst]
        int pos = r0 + atomicAdd(&cur[l], 1);
        rec2[pos] = make_int2((rv.x & 0x1FFFF) << 7, __float_as_int(cpart));  // src*128B
    }
}

// ---------- h1' = (x @ W1) * dinv[row], stored bf16 ----------
__global__ __launch_bounds__(256) void k_mm1(const float* __restrict__ x,
                                             const float* __restrict__ W1,
                                             const float* __restrict__ dinv,
                                             unsigned short* __restrict__ h1p) {
    int t = threadIdx.x, lane = t & 63, wv = t >> 6;
    int wid = blockIdx.x * 4 + wv, nw = gridDim.x * 4;
    float Wc[64];
#pragma unroll
    for (int k = 0; k < 64; ++k) Wc[k] = W1[k * 64 + lane];
    for (int r0 = wid * 4; r0 < N_NODES; r0 += nw * 4) {
        float x0 = x[(r0 + 0) * 64 + lane];
        float x1 = x[(r0 + 1) * 64 + lane];
        float x2 = x[(r0 + 2) * 64 + lane];
        float x3 = x[(r0 + 3) * 64 + lane];
        float d0 = dinv[r0 + 0], d1 = dinv[r0 + 1], d2 = dinv[r0 + 2], d3 = dinv[r0 + 3];
        float a0 = 0.f, a1 = 0.f, a2 = 0.f, a3 = 0.f;
#pragma unroll
        for (int k = 0; k < 64; ++k) {
            float wk = Wc[k];
            a0 = fmaf(rlane(x0, k), wk, a0);
            a1 = fmaf(rlane(x1, k), wk, a1);
            a2 = fmaf(rlane(x2, k), wk, a2);
            a3 = fmaf(rlane(x3, k), wk, a3);
        }
        h1p[(r0 + 0) * 64 + lane] = f2bf(a0 * d0);
        h1p[(r0 + 1) * 64 + lane] = f2bf(a1 * d1);
        h1p[(r0 + 2) * 64 + lane] = f2bf(a2 * d2);
        h1p[(r0 + 3) * 64 + lane] = f2bf(a3 * d3);
    }
}

// ---------- agg1: 4 edge-slots x 16 lanes, dwordx2 (4 cols) per lane ----------
__global__ __launch_bounds__(256) void k_agg1(const int* __restrict__ rowStart,
                                              const int2* __restrict__ rec2,
                                              const float* __restrict__ dinv,
                                              const unsigned short* __restrict__ h1p,
                                              float* __restrict__ agg1) {
    __shared__ int2 cache[4][64];
    int t = threadIdx.x, lane = t & 63, wv = t >> 6;
    int node = blockIdx.x * 4 + wv;
    if (node >= N_NODES) return;
    int2* wc = cache[wv];
    wc[lane] = make_int2(0, 0);           // defined offsets for stale slots
    const char* hb = (const char*)h1p;
    int eslot = lane >> 4;                // 0..3
    int c = lane & 15;                    // 8B chunk -> cols 4c..4c+3
    int lo = c << 3;
    float dn = dinv[node];
    float a0 = 0.f, a1 = 0.f, a2 = 0.f, a3 = 0.f;
    float b0 = 0.f, b1 = 0.f, b2v = 0.f, b3 = 0.f;
    if (eslot == 0) {                     // self loop only once
        const unsigned int* sp = (const unsigned int*)(hb + ((long)node << 7) + lo);
        unsigned int u0 = sp[0], u1 = sp[1];
        a0 = bflo(u0) * dn; a1 = bfhi(u0) * dn;
        a2 = bflo(u1) * dn; a3 = bfhi(u1) * dn;
    }
    int s0 = rowStart[node], s1 = rowStart[node + 1];
    for (int base = s0; base < s1; base += 64) {
        int idx = base + lane;
        if (idx < s1) wc[lane] = rec2[idx];
        __builtin_amdgcn_wave_barrier();
        int cnt = min(64, s1 - base);
        int j = 0;
        for (; j + 7 < cnt; j += 8) {
            int2 eA = wc[j + eslot];
            int2 eB = wc[j + 4 + eslot];
            const unsigned int* pA = (const unsigned int*)(hb + eA.x + lo);
            const unsigned int* pB = (const unsigned int*)(hb + eB.x + lo);
            unsigned int uA0 = pA[0], uA1 = pA[1];
            unsigned int uB0 = pB[0], uB1 = pB[1];
            float cA = __int_as_float(eA.y), cB = __int_as_float(eB.y);
            a0 = fmaf(bflo(uA0), cA, a0);
            a1 = fmaf(bfhi(uA0), cA, a1);
            a2 = fmaf(bflo(uA1), cA, a2);
            a3 = fmaf(bfhi(uA1), cA, a3);
            b0 = fmaf(bflo(uB0), cB, b0);
            b1 = fmaf(bfhi(uB0), cB, b1);
            b2v = fmaf(bflo(uB1), cB, b2v);
            b3 = fmaf(bfhi(uB1), cB, b3);
        }
        for (; j < cnt; j += 4) {
            int jj = j + eslot;
            bool valid = jj < cnt;
            int2 e = wc[valid ? jj : j];
            float cc = valid ? __int_as_float(e.y) : 0.f;
            const unsigned int* p = (const unsigned int*)(hb + e.x + lo);
            unsigned int u0 = p[0], u1 = p[1];
            a0 = fmaf(bflo(u0), cc, a0);
            a1 = fmaf(bfhi(u0), cc, a1);
            a2 = fmaf(bflo(u1), cc, a2);
            a3 = fmaf(bfhi(u1), cc, a3);
        }
        __builtin_amdgcn_wave_barrier();
    }
    a0 += b0; a1 += b1; a2 += b2v; a3 += b3;
    a0 += __shfl_xor(a0, 16, 64); a0 += __shfl_xor(a0, 32, 64);
    a1 += __shfl_xor(a1, 16, 64); a1 += __shfl_xor(a1, 32, 64);
    a2 += __shfl_xor(a2, 16, 64); a2 += __shfl_xor(a2, 32, 64);
    a3 += __shfl_xor(a3, 16, 64); a3 += __shfl_xor(a3, 32, 64);
    if (eslot == 0) {
        *(float4*)(agg1 + ((long)node << 6) + (c << 2)) = make_float4(a0, a1, a2, a3);
    }
}

// ---------- h2' = (relu(agg1+b1) @ W2) * dinv[row], bf16, 128B-padded rows ----------
__global__ __launch_bounds__(256) void k_mm2(const float* __restrict__ agg1,
                                             const float* __restrict__ b1,
                                             const float* __restrict__ W2,
                                             const float* __restrict__ dinv,
                                             unsigned short* __restrict__ h2p) {
    int t = threadIdx.x, lane = t & 63, wv = t >> 6;
    int wid = blockIdx.x * 4 + wv, nw = gridDim.x * 4;
    bool act = lane < C_DIM;
    float Wc[64];
#pragma unroll
    for (int k = 0; k < 64; ++k) Wc[k] = act ? W2[k * C_DIM + lane] : 0.f;
    float bv = b1[lane];
    for (int r0 = wid * 4; r0 < N_NODES; r0 += nw * 4) {
        float x0 = fmaxf(agg1[(r0 + 0) * 64 + lane] + bv, 0.f);
        float x1 = fmaxf(agg1[(r0 + 1) * 64 + lane] + bv, 0.f);
        float x2 = fmaxf(agg1[(r0 + 2) * 64 + lane] + bv, 0.f);
        float x3 = fmaxf(agg1[(r0 + 3) * 64 + lane] + bv, 0.f);
        float d0 = dinv[r0 + 0], d1 = dinv[r0 + 1], d2 = dinv[r0 + 2], d3 = dinv[r0 + 3];
        float a0 = 0.f, a1 = 0.f, a2 = 0.f, a3 = 0.f;
#pragma unroll
        for (int k = 0; k < 64; ++k) {
            float wk = Wc[k];
            a0 = fmaf(rlane(x0, k), wk, a0);
            a1 = fmaf(rlane(x1, k), wk, a1);
            a2 = fmaf(rlane(x2, k), wk, a2);
            a3 = fmaf(rlane(x3, k), wk, a3);
        }
        if (act) {
            h2p[(r0 + 0) * 64 + lane] = f2bf(a0 * d0);
            h2p[(r0 + 1) * 64 + lane] = f2bf(a1 * d1);
            h2p[(r0 + 2) * 64 + lane] = f2bf(a2 * d2);
            h2p[(r0 + 3) * 64 + lane] = f2bf(a3 * d3);
        }
    }
}

// ---------- agg2: 3 edge-slots x 20 lanes, dword (2 cols) per lane + softmax ----------
__global__ __launch_bounds__(256) void k_agg2(const int* __restrict__ rowStart,
                                              const int2* __restrict__ rec2,
                                              const float* __restrict__ dinv,
                                              const unsigned short* __restrict__ h2p,
                                              const float* __restrict__ b2,
                                              float* __restrict__ out) {
    __shared__ int2 cache[4][64];
    int t = threadIdx.x, lane = t & 63, wv = t >> 6;
    int node = blockIdx.x * 4 + wv;
    if (node >= N_NODES) return;
    int2* wc = cache[wv];
    wc[lane] = make_int2(0, 0);
    const char* hb = (const char*)h2p;
    int eslot = lane / 20;                // 0..3 (lanes 60..63 inactive)
    int c = lane - eslot * 20;            // 0..19 -> cols 2c,2c+1
    bool elane = eslot < 3;
    int lo = c << 2;
    float dn = dinv[node];
    float alo0 = 0.f, ahi0 = 0.f, alo1 = 0.f, ahi1 = 0.f;
    if (eslot == 0) {                     // self loop
        unsigned int u = *(const unsigned int*)(hb + ((long)node << 7) + lo);
        alo0 = bflo(u) * dn;
        ahi0 = bfhi(u) * dn;
    }
    int s0 = rowStart[node], s1 = rowStart[node + 1];
    for (int base = s0; base < s1; base += 64) {
        int idx = base + lane;
        if (idx < s1) wc[lane] = rec2[idx];
        __builtin_amdgcn_wave_barrier();
        int cnt = min(64, s1 - base);
        int j = 0;
        for (; j + 5 < cnt; j += 6) {
            int2 eA = wc[j + eslot];
            int2 eB = wc[j + 3 + eslot];
            unsigned int uA = *(const unsigned int*)(hb + eA.x + lo);
            unsigned int uB = *(const unsigned int*)(hb + eB.x + lo);
            float cA = elane ? __int_as_float(eA.y) : 0.f;
            float cB = elane ? __int_as_float(eB.y) : 0.f;
            alo0 = fmaf(bflo(uA), cA, alo0);
            ahi0 = fmaf(bfhi(uA), cA, ahi0);
            alo1 = fmaf(bflo(uB), cB, alo1);
            ahi1 = fmaf(bfhi(uB), cB, ahi1);
        }
        for (; j < cnt; j += 3) {
            int jj = j + eslot;
            bool valid = elane && (jj < cnt);
            int2 e = wc[valid ? jj : j];
            float cc = valid ? __int_as_float(e.y) : 0.f;
            unsigned int u = *(const unsigned int*)(hb + e.x + lo);
            alo0 = fmaf(bflo(u), cc, alo0);
            ahi0 = fmaf(bfhi(u), cc, ahi0);
        }
        __builtin_amdgcn_wave_barrier();
    }
    float alo = alo0 + alo1, ahi = ahi0 + ahi1;
    float t1 = __shfl(alo, lane + 20, 64), t2 = __shfl(alo, lane + 40, 64);
    float t3 = __shfl(ahi, lane + 20, 64), t4 = __shfl(ahi, lane + 40, 64);
    alo = alo + t1 + t2;
    ahi = ahi + t3 + t4;
    bool act = lane < 20;
    float2 bb = ((const float2*)b2)[c];
    float vlo = act ? alo + bb.x : -INFINITY;
    float vhi = act ? ahi + bb.y : -INFINITY;
    float m = fmaxf(vlo, vhi);
#pragma unroll
    for (int off = 32; off; off >>= 1) m = fmaxf(m, __shfl_xor(m, off, 64));
    float exlo = act ? expf(vlo - m) : 0.f;
    float exhi = act ? expf(vhi - m) : 0.f;
    float s = exlo + exhi;
#pragma unroll
    for (int off = 32; off; off >>= 1) s += __shfl_xor(s, off, 64);
    float ls = m + logf(s);
    if (act) {
        *(float2*)(out + (long)node * C_DIM + (c << 1)) = make_float2(vlo - ls, vhi - ls);
    }
}

extern "C" void kernel_launch(void* const* d_in, const int* in_sizes, int n_in,
                              void* d_out, int out_size, void* d_ws, size_t ws_size,
                              hipStream_t stream) {
    const float* x  = (const float*)d_in[0];
    const int*   ei = (const int*)d_in[1];
    const float* w  = (const float*)d_in[2];
    const float* W1 = (const float*)d_in[3];
    const float* b1 = (const float*)d_in[4];
    const float* W2 = (const float*)d_in[5];
    const float* b2 = (const float*)d_in[6];
    float* out = (float*)d_out;

    float* wsf = (float*)d_ws;
    int*   wsi = (int*)d_ws;
    float* dinv       = wsf + OFF_DINV;
    int*   bucketBase = wsi + OFF_BB;
    int*   colsum     = wsi + OFF_CS;
    int*   rowStart   = wsi + OFF_ROW;
    int*   H          = wsi + OFF_H;
    int2*  rec2       = (int2*)(wsi + OFF_REC2);
    int2*  rec        = (int2*)(wsi + OFF_H1P);              // dead before h1p written
    unsigned short* h1p = (unsigned short*)(wsi + OFF_H1P);
    unsigned short* h2p = (unsigned short*)(wsi + OFF_H2P);
    float* agg1       = wsf + OFF_AGG1;

    // CSR build — zero global atomics except 391-bin colsum
    hipMemsetAsync(colsum, 0, NB * sizeof(int), stream);
    k_hist2d<<<NBE, 512, 0, stream>>>(ei, H, colsum);
    k_colscan<<<NB, 512, 0, stream>>>(H, colsum, bucketBase, rowStart);
    k_scatter<<<NBE, 512, 0, stream>>>(ei, w, H, rec);
    k_bsort<<<NB, 512, 0, stream>>>(bucketBase, rec, rec2, dinv, rowStart);

    // layer 1
    k_mm1<<<512, 256, 0, stream>>>(x, W1, dinv, h1p);
    k_agg1<<<(N_NODES + 3) / 4, 256, 0, stream>>>(rowStart, rec2, dinv, h1p, agg1);

    // layer 2 (+ fused bias/log-softmax epilogue)
    k_mm2<<<512, 256, 0, stream>>>(agg1, b1, W2, dinv, h2p);
    k_agg2<<<(N_NODES + 3) / 4, 256, 0, stream>>>(rowStart, rec2, dinv, h2p, b2, out);
}

// Round 10
// 279.474 us; speedup vs baseline: 1.4160x; 1.1913x over previous
//
#include <hip/hip_runtime.h>
#include <math.h>

#define N_NODES 100000
#define N_EDGES 1600000
#define C_DIM 40
#define NGROUPS 6250                      // 100000 / 16 exactly

#define BSZ 256                           // nodes per bucket
#define NB  ((N_NODES + BSZ - 1) / BSZ)   // 391
#define EB  4096                          // edges per hist/scatter block
#define NBE ((N_EDGES + EB - 1) / EB)     // 391

// ---------------- workspace layout (4-byte units) ----------------
#define OFF_DINV 0                        // float[100000]
#define OFF_BB   100000                   // int[NB+1]
#define OFF_CS   100392                   // int[NB] column sums
#define OFF_ROW  100800                   // int[N+1]
#define OFF_H    200802                   // int[NBE*NB]
#define OFF_REC2 353684                   // int2[E] sorted records (even -> 8B aligned)
#define OFF_H1P  3553684                  // ushort[N*64] bf16 h1'; unsorted rec aliases here
#define OFF_H2P  6753684                  // ushort[N*64] bf16 h2' (128B padded rows)
#define OFF_AGG1 9953684                  // float[N*64]

typedef float floatx4 __attribute__((ext_vector_type(4)));
typedef short shortx8 __attribute__((ext_vector_type(8)));

__device__ inline unsigned short f2bf(float f) {
    unsigned int u = __float_as_uint(f);
    u += 0x7FFF + ((u >> 16) & 1);        // round to nearest even
    return (unsigned short)(u >> 16);
}
__device__ inline float bf2f(unsigned short h) {
    return __uint_as_float(((unsigned int)h) << 16);
}
__device__ inline float bflo(unsigned int u) { return __uint_as_float(u << 16); }
__device__ inline float bfhi(unsigned int u) { return __uint_as_float(u & 0xFFFF0000u); }

// ---------- per-block bucket histogram: H[b][j] + global column sums ----------
__global__ __launch_bounds__(512) void k_hist2d(const int* __restrict__ ei,
                                                int* __restrict__ H,
                                                int* __restrict__ colsum) {
    __shared__ int bins[NB];
    int t = threadIdx.x, b = blockIdx.x;
    for (int i = t; i < NB; i += 512) bins[i] = 0;
    __syncthreads();
    int base = b * EB;
    for (int i = t; i < EB; i += 512) {
        int e = base + i;
        if (e < N_EDGES) atomicAdd(&bins[ei[N_EDGES + e] >> 8], 1);
    }
    __syncthreads();
    for (int i = t; i < NB; i += 512) {
        int c = bins[i];
        H[b * NB + i] = c;
        if (c) atomicAdd(&colsum[i], c);
    }
}

// ---------- column scan (self-computes bucketBase[j] from colsum) ----------
__global__ __launch_bounds__(512) void k_colscan(int* __restrict__ H,
                                                 const int* __restrict__ colsum,
                                                 int* __restrict__ bucketBase,
                                                 int* __restrict__ rowStart) {
    __shared__ int sd[512];
    __shared__ int sbase;
    int t = threadIdx.x, j = blockIdx.x;
    int p = 0;
    for (int i = t; i < j; i += 512) p += colsum[i];
    sd[t] = p;
    __syncthreads();
    for (int off = 256; off > 0; off >>= 1) {
        if (t < off) sd[t] += sd[t + off];
        __syncthreads();
    }
    if (t == 0) sbase = sd[0];
    __syncthreads();
    int base = sbase;
    if (t == 0) {
        bucketBase[j] = base;
        if (j == NB - 1) { bucketBase[NB] = base + colsum[j]; rowStart[N_NODES] = N_EDGES; }
    }
    __syncthreads();
    int val = (t < NBE) ? H[t * NB + j] : 0;
    sd[t] = val;
    __syncthreads();
    for (int off = 1; off < 512; off <<= 1) {
        int v = (t >= off) ? sd[t - off] : 0;
        __syncthreads();
        sd[t] += v;
        __syncthreads();
    }
    if (t < NBE) H[t * NB + j] = base + sd[t] - val;
}

// ---------- scatter into bucket regions (LDS cursors, no global atomics) ----------
__global__ __launch_bounds__(512) void k_scatter(const int* __restrict__ ei,
                                                 const float* __restrict__ w,
                                                 const int* __restrict__ blockBase,
                                                 int2* __restrict__ rec) {
    __shared__ int bases[NB];
    __shared__ int cur[NB];
    int t = threadIdx.x, b = blockIdx.x;
    for (int i = t; i < NB; i += 512) { bases[i] = blockBase[b * NB + i]; cur[i] = 0; }
    __syncthreads();
    int base = b * EB;
    for (int i = t; i < EB; i += 512) {
        int e = base + i;
        if (e < N_EDGES) {
            int s = ei[e], d = ei[N_EDGES + e];
            float wv = w[e];
            int bin = d >> 8;
            int pos = bases[bin] + atomicAdd(&cur[bin], 1);
            rec[pos] = make_int2(s | ((d & 255) << 17), __float_as_int(wv));
        }
    }
}

// ---------- per-bucket counting sort; payload = w*dinv[dst]; x = src byte-offset ----------
__global__ __launch_bounds__(512) void k_bsort(const int* __restrict__ bucketBase,
                                               const int2* __restrict__ rec,
                                               int2* __restrict__ rec2,
                                               float* __restrict__ dinv,
                                               int* __restrict__ rowStart) {
    __shared__ int   cnt[256];
    __shared__ float wsum[256];
    __shared__ int   cur[256];
    __shared__ int   sd[512];
    int t = threadIdx.x, b = blockIdx.x;
    if (t < 256) { cnt[t] = 0; wsum[t] = 0.f; }
    __syncthreads();
    int r0 = bucketBase[b], r1 = bucketBase[b + 1];
    for (int i = r0 + t; i < r1; i += 512) {
        int2 rv = rec[i];
        int l = (rv.x >> 17) & 255;
        atomicAdd(&cnt[l], 1);
        atomicAdd(&wsum[l], __int_as_float(rv.y));
    }
    __syncthreads();
    int val = (t < 256) ? cnt[t] : 0;
    sd[t] = val;
    __syncthreads();
    for (int off = 1; off < 512; off <<= 1) {
        int v = (t >= off) ? sd[t - off] : 0;
        __syncthreads();
        sd[t] += v;
        __syncthreads();
    }
    float dloc = 0.f;
    if (t < 256) {
        int excl = sd[t] - val;
        cur[t] = excl;
        int node = b * BSZ + t;
        dloc = rsqrtf(1.f + wsum[t]);
        if (node < N_NODES) {
            rowStart[node] = r0 + excl;
            dinv[node] = dloc;
        }
    }
    __syncthreads();
    if (t < 256) wsum[t] = dloc;
    __syncthreads();
    for (int i = r0 + t; i < r1; i += 512) {
        int2 rv = rec[i];
        int l = (rv.x >> 17) & 255;
        float cpart = __int_as_float(rv.y) * wsum[l];   // w * dinv[dst]
        int pos = r0 + atomicAdd(&cur[l], 1);
        rec2[pos] = make_int2((rv.x & 0x1FFFF) << 7, __float_as_int(cpart));  // src*128B
    }
}

// ---------- h1' = (x @ W1) * dinv[row] via MFMA, stored bf16 ----------
// Wave = one 16-node group per grid-stride iter. A: m=lane&15, k=quad*8+j.
// B: n=lane&15, k=quad*8+j. D: col=lane&15, row=quad*4+reg (verified layout).
__global__ __launch_bounds__(256) void k_mm1(const float* __restrict__ x,
                                             const float* __restrict__ W1,
                                             const float* __restrict__ dinv,
                                             unsigned short* __restrict__ h1p) {
    int t = threadIdx.x, lane = t & 63, wv = t >> 6;
    int m = lane & 15, quad = lane >> 4;
    int wid = blockIdx.x * 4 + wv, nw = gridDim.x * 4;
    shortx8 B[2][4];
#pragma unroll
    for (int kc = 0; kc < 2; ++kc)
#pragma unroll
        for (int tt = 0; tt < 4; ++tt)
#pragma unroll
            for (int j = 0; j < 8; ++j) {
                int k = kc * 32 + quad * 8 + j;
                B[kc][tt][j] = (short)f2bf(W1[k * 64 + tt * 16 + m]);
            }
    for (int g = wid; g < NGROUPS; g += nw) {
        int n0 = g * 16;
        const float* xr = x + (long)(n0 + m) * 64 + quad * 8;
        floatx4 xa = ((const floatx4*)xr)[0];
        floatx4 xb = ((const floatx4*)(xr + 4))[0];
        floatx4 xc = ((const floatx4*)(xr + 32))[0];
        floatx4 xd = ((const floatx4*)(xr + 36))[0];
        shortx8 A0, A1;
#pragma unroll
        for (int j = 0; j < 4; ++j) {
            A0[j] = (short)f2bf(xa[j]);
            A0[4 + j] = (short)f2bf(xb[j]);
            A1[j] = (short)f2bf(xc[j]);
            A1[4 + j] = (short)f2bf(xd[j]);
        }
        floatx4 acc[4];
#pragma unroll
        for (int tt = 0; tt < 4; ++tt) {
            acc[tt] = (floatx4){0.f, 0.f, 0.f, 0.f};
            acc[tt] = __builtin_amdgcn_mfma_f32_16x16x32_bf16(A0, B[0][tt], acc[tt], 0, 0, 0);
            acc[tt] = __builtin_amdgcn_mfma_f32_16x16x32_bf16(A1, B[1][tt], acc[tt], 0, 0, 0);
        }
        floatx4 dv = ((const floatx4*)(dinv + n0 + quad * 4))[0];
#pragma unroll
        for (int reg = 0; reg < 4; ++reg) {
            int node = n0 + quad * 4 + reg;
            float d = dv[reg];
#pragma unroll
            for (int tt = 0; tt < 4; ++tt)
                h1p[(long)node * 64 + tt * 16 + m] = f2bf(acc[tt][reg] * d);
        }
    }
}

// ---------- agg1: 4 edge-slots x 16 lanes, dwordx2 (4 cols) per lane ----------
__global__ __launch_bounds__(256) void k_agg1(const int* __restrict__ rowStart,
                                              const int2* __restrict__ rec2,
                                              const float* __restrict__ dinv,
                                              const unsigned short* __restrict__ h1p,
                                              float* __restrict__ agg1) {
    __shared__ int2 cache[4][64];
    int t = threadIdx.x, lane = t & 63, wv = t >> 6;
    int node = blockIdx.x * 4 + wv;
    if (node >= N_NODES) return;
    int2* wc = cache[wv];
    wc[lane] = make_int2(0, 0);
    const char* hb = (const char*)h1p;
    int eslot = lane >> 4;
    int c = lane & 15;
    int lo = c << 3;
    float dn = dinv[node];
    float a0 = 0.f, a1 = 0.f, a2 = 0.f, a3 = 0.f;
    float b0 = 0.f, b1 = 0.f, b2v = 0.f, b3 = 0.f;
    if (eslot == 0) {
        const unsigned int* sp = (const unsigned int*)(hb + ((long)node << 7) + lo);
        unsigned int u0 = sp[0], u1 = sp[1];
        a0 = bflo(u0) * dn; a1 = bfhi(u0) * dn;
        a2 = bflo(u1) * dn; a3 = bfhi(u1) * dn;
    }
    int s0 = rowStart[node], s1 = rowStart[node + 1];
    for (int base = s0; base < s1; base += 64) {
        int idx = base + lane;
        if (idx < s1) wc[lane] = rec2[idx];
        __builtin_amdgcn_wave_barrier();
        int cnt = min(64, s1 - base);
        int j = 0;
        for (; j + 7 < cnt; j += 8) {
            int2 eA = wc[j + eslot];
            int2 eB = wc[j + 4 + eslot];
            const unsigned int* pA = (const unsigned int*)(hb + eA.x + lo);
            const unsigned int* pB = (const unsigned int*)(hb + eB.x + lo);
            unsigned int uA0 = pA[0], uA1 = pA[1];
            unsigned int uB0 = pB[0], uB1 = pB[1];
            float cA = __int_as_float(eA.y), cB = __int_as_float(eB.y);
            a0 = fmaf(bflo(uA0), cA, a0);
            a1 = fmaf(bfhi(uA0), cA, a1);
            a2 = fmaf(bflo(uA1), cA, a2);
            a3 = fmaf(bfhi(uA1), cA, a3);
            b0 = fmaf(bflo(uB0), cB, b0);
            b1 = fmaf(bfhi(uB0), cB, b1);
            b2v = fmaf(bflo(uB1), cB, b2v);
            b3 = fmaf(bfhi(uB1), cB, b3);
        }
        for (; j < cnt; j += 4) {
            int jj = j + eslot;
            bool valid = jj < cnt;
            int2 e = wc[valid ? jj : j];
            float cc = valid ? __int_as_float(e.y) : 0.f;
            const unsigned int* p = (const unsigned int*)(hb + e.x + lo);
            unsigned int u0 = p[0], u1 = p[1];
            a0 = fmaf(bflo(u0), cc, a0);
            a1 = fmaf(bfhi(u0), cc, a1);
            a2 = fmaf(bflo(u1), cc, a2);
            a3 = fmaf(bfhi(u1), cc, a3);
        }
        __builtin_amdgcn_wave_barrier();
    }
    a0 += b0; a1 += b1; a2 += b2v; a3 += b3;
    a0 += __shfl_xor(a0, 16, 64); a0 += __shfl_xor(a0, 32, 64);
    a1 += __shfl_xor(a1, 16, 64); a1 += __shfl_xor(a1, 32, 64);
    a2 += __shfl_xor(a2, 16, 64); a2 += __shfl_xor(a2, 32, 64);
    a3 += __shfl_xor(a3, 16, 64); a3 += __shfl_xor(a3, 32, 64);
    if (eslot == 0) {
        *(float4*)(agg1 + ((long)node << 6) + (c << 2)) = make_float4(a0, a1, a2, a3);
    }
}

// ---------- h2' = (relu(agg1+b1) @ W2) * dinv via MFMA, bf16, 128B-padded rows ----------
__global__ __launch_bounds__(256) void k_mm2(const float* __restrict__ agg1,
                                             const float* __restrict__ b1,
                                             const float* __restrict__ W2,
                                             const float* __restrict__ dinv,
                                             unsigned short* __restrict__ h2p) {
    int t = threadIdx.x, lane = t & 63, wv = t >> 6;
    int m = lane & 15, quad = lane >> 4;
    int wid = blockIdx.x * 4 + wv, nw = gridDim.x * 4;
    shortx8 B[2][3];
#pragma unroll
    for (int kc = 0; kc < 2; ++kc)
#pragma unroll
        for (int tt = 0; tt < 3; ++tt) {
            int n = tt * 16 + m;
#pragma unroll
            for (int j = 0; j < 8; ++j) {
                int k = kc * 32 + quad * 8 + j;
                B[kc][tt][j] = (n < C_DIM) ? (short)f2bf(W2[k * C_DIM + n]) : (short)0;
            }
        }
    floatx4 ba0 = ((const floatx4*)(b1 + quad * 8))[0];
    floatx4 ba1 = ((const floatx4*)(b1 + quad * 8 + 4))[0];
    floatx4 bb0 = ((const floatx4*)(b1 + 32 + quad * 8))[0];
    floatx4 bb1 = ((const floatx4*)(b1 + 32 + quad * 8 + 4))[0];
    for (int g = wid; g < NGROUPS; g += nw) {
        int n0 = g * 16;
        const float* xr = agg1 + (long)(n0 + m) * 64 + quad * 8;
        floatx4 xa = ((const floatx4*)xr)[0];
        floatx4 xb = ((const floatx4*)(xr + 4))[0];
        floatx4 xc = ((const floatx4*)(xr + 32))[0];
        floatx4 xd = ((const floatx4*)(xr + 36))[0];
        shortx8 A0, A1;
#pragma unroll
        for (int j = 0; j < 4; ++j) {
            A0[j]     = (short)f2bf(fmaxf(xa[j] + ba0[j], 0.f));
            A0[4 + j] = (short)f2bf(fmaxf(xb[j] + ba1[j], 0.f));
            A1[j]     = (short)f2bf(fmaxf(xc[j] + bb0[j], 0.f));
            A1[4 + j] = (short)f2bf(fmaxf(xd[j] + bb1[j], 0.f));
        }
        floatx4 acc[3];
#pragma unroll
        for (int tt = 0; tt < 3; ++tt) {
            acc[tt] = (floatx4){0.f, 0.f, 0.f, 0.f};
            acc[tt] = __builtin_amdgcn_mfma_f32_16x16x32_bf16(A0, B[0][tt], acc[tt], 0, 0, 0);
            acc[tt] = __builtin_amdgcn_mfma_f32_16x16x32_bf16(A1, B[1][tt], acc[tt], 0, 0, 0);
        }
        floatx4 dv = ((const floatx4*)(dinv + n0 + quad * 4))[0];
#pragma unroll
        for (int reg = 0; reg < 4; ++reg) {
            int node = n0 + quad * 4 + reg;
            float d = dv[reg];
#pragma unroll
            for (int tt = 0; tt < 3; ++tt) {
                int col = tt * 16 + m;
                if (col < C_DIM)
                    h2p[(long)node * 64 + col] = f2bf(acc[tt][reg] * d);
            }
        }
    }
}

// ---------- agg2: 3 edge-slots x 20 lanes, dword (2 cols) per lane + softmax ----------
__global__ __launch_bounds__(256) void k_agg2(const int* __restrict__ rowStart,
                                              const int2* __restrict__ rec2,
                                              const float* __restrict__ dinv,
                                              const unsigned short* __restrict__ h2p,
                                              const float* __restrict__ b2,
                                              float* __restrict__ out) {
    __shared__ int2 cache[4][64];
    int t = threadIdx.x, lane = t & 63, wv = t >> 6;
    int node = blockIdx.x * 4 + wv;
    if (node >= N_NODES) return;
    int2* wc = cache[wv];
    wc[lane] = make_int2(0, 0);
    const char* hb = (const char*)h2p;
    int eslot = lane / 20;
    int c = lane - eslot * 20;
    bool elane = eslot < 3;
    int lo = c << 2;
    float dn = dinv[node];
    float alo0 = 0.f, ahi0 = 0.f, alo1 = 0.f, ahi1 = 0.f;
    if (eslot == 0) {
        unsigned int u = *(const unsigned int*)(hb + ((long)node << 7) + lo);
        alo0 = bflo(u) * dn;
        ahi0 = bfhi(u) * dn;
    }
    int s0 = rowStart[node], s1 = rowStart[node + 1];
    for (int base = s0; base < s1; base += 64) {
        int idx = base + lane;
        if (idx < s1) wc[lane] = rec2[idx];
        __builtin_amdgcn_wave_barrier();
        int cnt = min(64, s1 - base);
        int j = 0;
        for (; j + 5 < cnt; j += 6) {
            int2 eA = wc[j + eslot];
            int2 eB = wc[j + 3 + eslot];
            unsigned int uA = *(const unsigned int*)(hb + eA.x + lo);
            unsigned int uB = *(const unsigned int*)(hb + eB.x + lo);
            float cA = elane ? __int_as_float(eA.y) : 0.f;
            float cB = elane ? __int_as_float(eB.y) : 0.f;
            alo0 = fmaf(bflo(uA), cA, alo0);
            ahi0 = fmaf(bfhi(uA), cA, ahi0);
            alo1 = fmaf(bflo(uB), cB, alo1);
            ahi1 = fmaf(bfhi(uB), cB, ahi1);
        }
        for (; j < cnt; j += 3) {
            int jj = j + eslot;
            bool valid = elane && (jj < cnt);
            int2 e = wc[valid ? jj : j];
            float cc = valid ? __int_as_float(e.y) : 0.f;
            unsigned int u = *(const unsigned int*)(hb + e.x + lo);
            alo0 = fmaf(bflo(u), cc, alo0);
            ahi0 = fmaf(bfhi(u), cc, ahi0);
        }
        __builtin_amdgcn_wave_barrier();
    }
    float alo = alo0 + alo1, ahi = ahi0 + ahi1;
    float t1 = __shfl(alo, lane + 20, 64), t2 = __shfl(alo, lane + 40, 64);
    float t3 = __shfl(ahi, lane + 20, 64), t4 = __shfl(ahi, lane + 40, 64);
    alo = alo + t1 + t2;
    ahi = ahi + t3 + t4;
    bool act = lane < 20;
    float2 bb = ((const float2*)b2)[c];
    float vlo = act ? alo + bb.x : -INFINITY;
    float vhi = act ? ahi + bb.y : -INFINITY;
    float m = fmaxf(vlo, vhi);
#pragma unroll
    for (int off = 32; off; off >>= 1) m = fmaxf(m, __shfl_xor(m, off, 64));
    float exlo = act ? expf(vlo - m) : 0.f;
    float exhi = act ? expf(vhi - m) : 0.f;
    float s = exlo + exhi;
#pragma unroll
    for (int off = 32; off; off >>= 1) s += __shfl_xor(s, off, 64);
    float ls = m + logf(s);
    if (act) {
        *(float2*)(out + (long)node * C_DIM + (c << 1)) = make_float2(vlo - ls, vhi - ls);
    }
}

extern "C" void kernel_launch(void* const* d_in, const int* in_sizes, int n_in,
                              void* d_out, int out_size, void* d_ws, size_t ws_size,
                              hipStream_t stream) {
    const float* x  = (const float*)d_in[0];
    const int*   ei = (const int*)d_in[1];
    const float* w  = (const float*)d_in[2];
    const float* W1 = (const float*)d_in[3];
    const float* b1 = (const float*)d_in[4];
    const float* W2 = (const float*)d_in[5];
    const float* b2 = (const float*)d_in[6];
    float* out = (float*)d_out;

    float* wsf = (float*)d_ws;
    int*   wsi = (int*)d_ws;
    float* dinv       = wsf + OFF_DINV;
    int*   bucketBase = wsi + OFF_BB;
    int*   colsum     = wsi + OFF_CS;
    int*   rowStart   = wsi + OFF_ROW;
    int*   H          = wsi + OFF_H;
    int2*  rec2       = (int2*)(wsi + OFF_REC2);
    int2*  rec        = (int2*)(wsi + OFF_H1P);              // dead before h1p written
    unsigned short* h1p = (unsigned short*)(wsi + OFF_H1P);
    unsigned short* h2p = (unsigned short*)(wsi + OFF_H2P);
    float* agg1       = wsf + OFF_AGG1;

    // CSR build — zero global atomics except 391-bin colsum
    hipMemsetAsync(colsum, 0, NB * sizeof(int), stream);
    k_hist2d<<<NBE, 512, 0, stream>>>(ei, H, colsum);
    k_colscan<<<NB, 512, 0, stream>>>(H, colsum, bucketBase, rowStart);
    k_scatter<<<NBE, 512, 0, stream>>>(ei, w, H, rec);
    k_bsort<<<NB, 512, 0, stream>>>(bucketBase, rec, rec2, dinv, rowStart);

    // layer 1 (MFMA matmul)
    k_mm1<<<512, 256, 0, stream>>>(x, W1, dinv, h1p);
    k_agg1<<<(N_NODES + 3) / 4, 256, 0, stream>>>(rowStart, rec2, dinv, h1p, agg1);

    // layer 2 (MFMA matmul + fused bias/log-softmax epilogue)
    k_mm2<<<512, 256, 0, stream>>>(agg1, b1, W2, dinv, h2p);
    k_agg2<<<(N_NODES + 3) / 4, 256, 0, stream>>>(rowStart, rec2, dinv, h2p, b2, out);
}